// Round 5
// baseline (161.116 us; speedup 1.0000x reference)
//
#include <hip/hip_runtime.h>
#include <hip/hip_bf16.h>
#include <stdint.h>
#include <math.h>

#define SEQ   1024
#define NHEAD 12
#define HD    64
#define CDIM  768
#define MTOK  8192
#define NQKV  2304
#define NPAIR 96   // BS*NHEAD

// q pre-scale: 1/sqrt(64) * log2(e)  (softmax done base-2)
#define QSCALE 0.18033688011112042f

typedef uint16_t u16;
typedef __attribute__((ext_vector_type(8))) __bf16 bf16x8;
typedef __attribute__((ext_vector_type(4))) float  f32x4;

__device__ __forceinline__ u16 f32_to_bf16(float f) {
  union { float f; uint32_t u; } cv; cv.f = f;
  uint32_t u = cv.u;
  return (u16)((u + 0x7FFFu + ((u >> 16) & 1u)) >> 16);
}

__device__ __forceinline__ uint32_t cvt_pk_bf16(float lo, float hi) {
  uint32_t r;
  asm("v_cvt_pk_bf16_f32 %0, %1, %2" : "=v"(r) : "v"(lo), "v"(hi));
  return r;
}

__device__ __forceinline__ void load_lds16(const u16* g, u16* l) {
  __builtin_amdgcn_global_load_lds(
      (const __attribute__((address_space(1))) uint32_t*)g,
      (__attribute__((address_space(3))) uint32_t*)l, 16, 0, 0);
}

// swizzled LDS read: 16B at (row, col-byte cb) of a 128B-row tile
__device__ __forceinline__ bf16x8 ldsw(const u16* base, int r, int cb) {
  int byte = (r << 7) + cb;
  byte ^= ((r & 7) << 4);
  return *(const bf16x8*)((const char*)base + byte);
}

// stage NB bytes (rows of 128B) from contiguous global, swizzled
template<int NB>
__device__ __forceinline__ void stage_swz(const u16* __restrict__ g, u16* l, int tid) {
  #pragma unroll
  for (int i = 0; i < NB / 4096; ++i) {
    int F = i * 4096 + tid * 16;
    int S = F ^ (((F >> 7) & 7) << 4);
    load_lds16(g + (S >> 1), l + (F >> 1));
  }
}

// stage V^T chunk: global vt[pair][d=64][n=1024], cols kc*64..+63 -> 64x128B tile
__device__ __forceinline__ void stage_vt(const u16* __restrict__ vtb, u16* l, int kc, int tid) {
  #pragma unroll
  for (int i = 0; i < 2; ++i) {
    int F = i * 4096 + tid * 16;
    int S = F ^ (((F >> 7) & 7) << 4);
    int r = S >> 7;
    int cb = S & 127;
    load_lds16(vtb + ((size_t)r << 10) + (kc << 6) + (cb >> 1), l + (F >> 1));
  }
}

// ---- convert x (fp32) -> bf16, 8 elems/thread ----
__global__ __launch_bounds__(256) void cvt_x_kernel(const float* __restrict__ in,
                                                    u16* __restrict__ out) {
  int i = blockIdx.x * 256 + threadIdx.x;
  const float4* p = (const float4*)in + (size_t)i * 2;
  float4 a = p[0], b = p[1];
  uint4 o;
  o.x = cvt_pk_bf16(a.x, a.y);
  o.y = cvt_pk_bf16(a.z, a.w);
  o.z = cvt_pk_bf16(b.x, b.y);
  o.w = cvt_pk_bf16(b.z, b.w);
  ((uint4*)out)[i] = o;
}

// ---- LDS-tiled transpose+convert: in [K][N] fp32 -> out [N][K] bf16 ----
__global__ __launch_bounds__(256) void transpose_cvt_kernel(const float* __restrict__ in,
                                                            u16* __restrict__ out,
                                                            int K, int N) {
  __shared__ u16 t[64][66];
  int nbk = K >> 6;
  int bk = blockIdx.x % nbk, bn = blockIdx.x / nbk;
  int k0 = bk << 6, n0 = bn << 6;
  int tid = threadIdx.x;
  #pragma unroll
  for (int i = 0; i < 16; ++i) {
    int idx = i * 256 + tid;
    int kr = idx >> 6, nc = idx & 63;
    t[kr][nc] = f32_to_bf16(in[(size_t)(k0 + kr) * N + n0 + nc]);
  }
  __syncthreads();
  #pragma unroll
  for (int i = 0; i < 16; ++i) {
    int idx = i * 256 + tid;
    int nr = idx >> 6, kc = idx & 63;
    out[(size_t)(n0 + nr) * K + k0 + kc] = t[kc][nr];
  }
}

// ---- bf16 GEMM, A[M][K] @ Bt[N][K]^T, 128x128 tile, BK=64, 4 waves ----
template<int EPI>
__global__ __launch_bounds__(256) void gemm_bt(const u16* __restrict__ A,
                                               const u16* __restrict__ Bt,
                                               float* __restrict__ Cf,
                                               u16* __restrict__ qb,
                                               u16* __restrict__ kb,
                                               u16* __restrict__ vb,
                                               int M, int N, int K, int cpx) {
  __shared__ u16 As[2][128 * 64];
  __shared__ u16 Bs[2][128 * 64];

  int bid = blockIdx.x;
  int wgid = (bid & 7) * cpx + (bid >> 3);
  const int ntn = N >> 7;
  int tm = wgid / ntn, tn = wgid - tm * ntn;
  int mBase = tm << 7, nBase = tn << 7;
  int tid = threadIdx.x;
  int lane = tid & 63, wid = tid >> 6;
  int wr = (wid >> 1) << 6, wc = (wid & 1) << 6;
  int lr = lane & 15, lk = lane >> 4;

  const int nk = K >> 6;

  auto STAGE = [&](int kt, int b) {
    #pragma unroll
    for (int i = 0; i < 4; ++i) {
      int F = i * 4096 + tid * 16;
      int row = F >> 7;
      int cb  = (F & 127) ^ ((row & 7) << 4);
      load_lds16(A + (size_t)(mBase + row) * K + kt * 64 + (cb >> 1), &As[b][F >> 1]);
    }
    #pragma unroll
    for (int i = 0; i < 4; ++i) {
      int F = i * 4096 + tid * 16;
      int row = F >> 7;
      int cb  = (F & 127) ^ ((row & 7) << 4);
      load_lds16(Bt + (size_t)(nBase + row) * K + kt * 64 + (cb >> 1), &Bs[b][F >> 1]);
    }
  };

  f32x4 acc[4][4] = {};

  STAGE(0, 0);
  for (int kt = 0; kt < nk; ++kt) {
    const int cur = kt & 1;
    if (kt + 1 < nk) {
      STAGE(kt + 1, cur ^ 1);
      asm volatile("s_waitcnt vmcnt(8)" ::: "memory");
    } else {
      asm volatile("s_waitcnt vmcnt(0)" ::: "memory");
    }
    __builtin_amdgcn_s_barrier();
    asm volatile("" ::: "memory");

    #pragma unroll
    for (int kk = 0; kk < 2; ++kk) {
      bf16x8 af[4], bfr[4];
      #pragma unroll
      for (int i = 0; i < 4; ++i)
        af[i]  = ldsw(As[cur], wr + i * 16 + lr, kk * 64 + lk * 16);
      #pragma unroll
      for (int i = 0; i < 4; ++i)
        bfr[i] = ldsw(Bs[cur], wc + i * 16 + lr, kk * 64 + lk * 16);
      #pragma unroll
      for (int mi = 0; mi < 4; ++mi)
        #pragma unroll
        for (int ni = 0; ni < 4; ++ni)
          acc[mi][ni] = __builtin_amdgcn_mfma_f32_16x16x32_bf16(af[mi], bfr[ni], acc[mi][ni], 0, 0, 0);
    }

    __builtin_amdgcn_s_barrier();
    asm volatile("" ::: "memory");
  }

  #pragma unroll
  for (int mi = 0; mi < 4; ++mi)
    #pragma unroll
    for (int ni = 0; ni < 4; ++ni)
      #pragma unroll
      for (int j = 0; j < 4; ++j) {
        int m = mBase + wr + mi * 16 + lk * 4 + j;
        int c = nBase + wc + ni * 16 + lr;
        float val = acc[mi][ni][j];
        if (EPI == 0) {
          int s = c / CDIM, rem = c - s * CDIM;
          int h = rem >> 6, d = rem & 63;
          int bb = m >> 10, nn = m & 1023;
          size_t pbase = ((size_t)(bb * NHEAD + h)) << 16;
          if (s == 0)      qb[pbase + (nn << 6) + d] = f32_to_bf16(val * QSCALE);
          else if (s == 1) kb[pbase + (nn << 6) + d] = f32_to_bf16(val);
          else             vb[pbase + ((size_t)d << 10) + nn] = f32_to_bf16(val);
        } else {
          Cf[(size_t)m * N + c] = val;
        }
      }
}

// ---- flash attention: QBLK=128, 4 waves x 2 groups of 16 q-rows ----
// XCD-chunked block order (pairs local to an XCD -> KV lives in its L2);
// K/V LDS fragments shared across both q-groups; defer-max; setprio on MFMA.
__global__ __launch_bounds__(256) void attn_kernel(const u16* __restrict__ q,
                                                   const u16* __restrict__ k,
                                                   const u16* __restrict__ v,
                                                   u16* __restrict__ out) {
  __shared__ u16 QPs[128 * 64];     // 16KB: Q tile, then P (wave w: rows w*32..+31)
  __shared__ u16 Ks[2][64 * 64];
  __shared__ u16 Vs[2][64 * 64];    // V^T chunks

  int bid = blockIdx.x;
  int wgid = (bid & 7) * 96 + (bid >> 3);   // XCD x owns pairs 12x..12x+11
  int pair = wgid >> 3;
  int qt   = wgid & 7;                      // 8 q-tiles of 128 rows
  int b = pair / NHEAD, h = pair - b * NHEAD;
  const u16* Qg  = q + ((size_t)pair << 16) + (qt << 13);
  const u16* Kg  = k + ((size_t)pair << 16);
  const u16* Vtb = v + ((size_t)pair << 16);
  int tid = threadIdx.x, lane = tid & 63, wid = tid >> 6;
  int lr = lane & 15, lk = lane >> 4;

  stage_swz<16384>(Qg, QPs, tid);
  stage_swz<8192>(Kg, Ks[0], tid);
  stage_vt(Vtb, Vs[0], 0, tid);
  __syncthreads();

  // hoist Q fragments (2 groups); QPs then reused as wave-private P storage
  bf16x8 aq[2][2];
  #pragma unroll
  for (int g = 0; g < 2; ++g) {
    aq[g][0] = ldsw(QPs, wid * 32 + g * 16 + lr, lk * 16);
    aq[g][1] = ldsw(QPs, wid * 32 + g * 16 + lr, 64 + lk * 16);
  }
  u16* Pa = QPs + wid * 2048;   // 4KB per wave; group g at +g*1024 elems

  float m_[2] = {-1e30f, -1e30f}, l_[2] = {0.f, 0.f};
  f32x4 acc_o[2][4] = {};

  for (int kc = 0; kc < 16; ++kc) {
    const int cur = kc & 1;
    if (kc < 15) {
      stage_swz<8192>(Kg + ((kc + 1) << 12), Ks[cur ^ 1], tid);
      stage_vt(Vtb, Vs[cur ^ 1], kc + 1, tid);
    }

    // S^T = K Q^T, K-fragment shared across both q-groups
    f32x4 s[2][4] = {};
    __builtin_amdgcn_s_setprio(1);
    #pragma unroll
    for (int kk = 0; kk < 2; ++kk)
      #pragma unroll
      for (int ni = 0; ni < 4; ++ni) {
        bf16x8 ak = ldsw(Ks[cur], ni * 16 + lr, kk * 64 + lk * 16);
        s[0][ni] = __builtin_amdgcn_mfma_f32_16x16x32_bf16(ak, aq[0][kk], s[0][ni], 0, 0, 0);
        s[1][ni] = __builtin_amdgcn_mfma_f32_16x16x32_bf16(ak, aq[1][kk], s[1][ni], 0, 0, 0);
      }
    __builtin_amdgcn_s_setprio(0);

    #pragma unroll
    for (int g = 0; g < 2; ++g) {
      // in-lane row max over 16 values, reduce across the 4 dup lanes
      float mx01 = fmaxf(fmaxf(s[g][0][0], s[g][0][1]), fmaxf(s[g][0][2], s[g][0][3]));
      float mx23 = fmaxf(fmaxf(s[g][1][0], s[g][1][1]), fmaxf(s[g][1][2], s[g][1][3]));
      float mx45 = fmaxf(fmaxf(s[g][2][0], s[g][2][1]), fmaxf(s[g][2][2], s[g][2][3]));
      float mx67 = fmaxf(fmaxf(s[g][3][0], s[g][3][1]), fmaxf(s[g][3][2], s[g][3][3]));
      float mx = fmaxf(fmaxf(mx01, mx23), fmaxf(mx45, mx67));
      mx = fmaxf(mx, __shfl_xor(mx, 16, 64));
      mx = fmaxf(mx, __shfl_xor(mx, 32, 64));

      // defer-max: only rescale when some row's max grew by > 8 (log2 units)
      if (!__all(mx - m_[g] <= 8.f)) {
        float newm = fmaxf(m_[g], mx);
        float alpha = exp2f(m_[g] - newm);
        m_[g] = newm;
        l_[g] *= alpha;
        f32x4 av;
        #pragma unroll
        for (int j = 0; j < 4; ++j) av[j] = __shfl(alpha, lk * 4 + j, 64);
        #pragma unroll
        for (int ni = 0; ni < 4; ++ni) acc_o[g][ni] *= av;
      }

      #pragma unroll
      for (int ni = 0; ni < 4; ++ni)
        #pragma unroll
        for (int j = 0; j < 4; ++j)
          s[g][ni][j] = exp2f(s[g][ni][j] - m_[g]);

      float rs0 = (s[g][0][0] + s[g][0][1]) + (s[g][0][2] + s[g][0][3]);
      float rs1 = (s[g][1][0] + s[g][1][1]) + (s[g][1][2] + s[g][1][3]);
      float rs2 = (s[g][2][0] + s[g][2][1]) + (s[g][2][2] + s[g][2][3]);
      float rs3 = (s[g][3][0] + s[g][3][1]) + (s[g][3][2] + s[g][3][3]);
      float rs = (rs0 + rs1) + (rs2 + rs3);
      rs += __shfl_xor(rs, 16, 64);
      rs += __shfl_xor(rs, 32, 64);
      l_[g] += rs;

      // pack P row (q=lr) into wave-private LDS region
      #pragma unroll
      for (int ni = 0; ni < 4; ++ni) {
        uint32_t w0 = cvt_pk_bf16(s[g][ni][0], s[g][ni][1]);
        uint32_t w1 = cvt_pk_bf16(s[g][ni][2], s[g][ni][3]);
        int byte = (g << 11) + (lr << 7) + (ni << 5) + (lk << 3);
        byte ^= ((lr & 7) << 4);
        uint2 wv; wv.x = w0; wv.y = w1;
        *(uint2*)((char*)Pa + byte) = wv;
      }
    }

    // O += P V, V-fragment shared across both q-groups
    bf16x8 ap[2][2];
    #pragma unroll
    for (int g = 0; g < 2; ++g) {
      ap[g][0] = ldsw(Pa + g * 1024, lr, lk * 16);
      ap[g][1] = ldsw(Pa + g * 1024, lr, 64 + lk * 16);
    }
    __builtin_amdgcn_s_setprio(1);
    #pragma unroll
    for (int kk = 0; kk < 2; ++kk)
      #pragma unroll
      for (int ni = 0; ni < 4; ++ni) {
        bf16x8 bv = ldsw(Vs[cur], ni * 16 + lr, kk * 64 + lk * 16);
        acc_o[0][ni] = __builtin_amdgcn_mfma_f32_16x16x32_bf16(ap[0][kk], bv, acc_o[0][ni], 0, 0, 0);
        acc_o[1][ni] = __builtin_amdgcn_mfma_f32_16x16x32_bf16(ap[1][kk], bv, acc_o[1][ni], 0, 0, 0);
      }
    __builtin_amdgcn_s_setprio(0);
    __syncthreads();
  }

  // epilogue: normalize, write bf16 attn_out [tok][c]
  #pragma unroll
  for (int g = 0; g < 2; ++g) {
    float il = 1.f / l_[g];
    f32x4 ilv;
    #pragma unroll
    for (int j = 0; j < 4; ++j) ilv[j] = __shfl(il, lk * 4 + j, 64);
    #pragma unroll
    for (int ni = 0; ni < 4; ++ni)
      #pragma unroll
      for (int j = 0; j < 4; ++j) {
        int qrow = (qt << 7) + wid * 32 + g * 16 + lk * 4 + j;
        int c = h * 64 + ni * 16 + lr;
        out[((size_t)(b * SEQ + qrow)) * CDIM + c] = f32_to_bf16(acc_o[g][ni][j] * ilv[j]);
      }
  }
}

extern "C" void kernel_launch(void* const* d_in, const int* in_sizes, int n_in,
                              void* d_out, int out_size, void* d_ws, size_t ws_size,
                              hipStream_t stream) {
  const float* x     = (const float*)d_in[0];
  const float* w_qkv = (const float*)d_in[1];
  const float* w_o   = (const float*)d_in[2];
  float* out = (float*)d_out;

  u16* xb    = (u16*)d_ws;
  u16* wqkvT = xb    + (size_t)MTOK * CDIM;
  u16* woT   = wqkvT + (size_t)NQKV * CDIM;
  u16* qb    = woT   + (size_t)CDIM * CDIM;
  u16* kb    = qb    + (size_t)NPAIR * SEQ * HD;
  u16* vb    = kb    + (size_t)NPAIR * SEQ * HD;   // stored transposed: [pair][d][n]
  u16* ao    = vb    + (size_t)NPAIR * SEQ * HD;

  cvt_x_kernel<<<dim3((MTOK * CDIM) / (256 * 8)), 256, 0, stream>>>(x, xb);
  transpose_cvt_kernel<<<dim3((CDIM / 64) * (NQKV / 64)), 256, 0, stream>>>(w_qkv, wqkvT, CDIM, NQKV);
  transpose_cvt_kernel<<<dim3((CDIM / 64) * (CDIM / 64)), 256, 0, stream>>>(w_o, woT, CDIM, CDIM);

  {
    int nwg = (MTOK / 128) * (NQKV / 128);   // 1152, %8==0
    gemm_bt<0><<<dim3(nwg), 256, 0, stream>>>(
        xb, wqkvT, nullptr, qb, kb, vb, MTOK, NQKV, CDIM, nwg / 8);
  }

  attn_kernel<<<dim3(NPAIR * 8), 256, 0, stream>>>(qb, kb, vb, ao);

  {
    int nwg = (MTOK / 128) * (CDIM / 128);   // 384, %8==0
    gemm_bt<1><<<dim3(nwg), 256, 0, stream>>>(
        ao, woT, out, nullptr, nullptr, nullptr, MTOK, CDIM, CDIM, nwg / 8);
  }
}